// Round 3
// baseline (365.088 us; speedup 1.0000x reference)
//
#include <hip/hip_runtime.h>

// Problem constants
#define B_   32
#define Q_   40
#define L_   1024
#define H_   1024
#define QQ_  80
#define M_   1280          // B_*Q_
#define K3_  3072
#define JK_  2048          // joint holds only the two pooled-feature thirds

// Workspace layout (BYTE offsets)
#define OB_W0T   0u                              // bf16 [1024][3072]  6291456
#define OB_WT2   6291456u                        // bf16 [B][80][L]    5242880
#define OB_JOINT 11534336u                       // bf16 [M][2048]     5242880
#define OB_PART  16777216u                       // bf16 [4][M][1024] 10485760
#define OB_TXTB  27262976u                       // bf16 [32][1024]      65536
#define OB_TXTP  27328512u                       // bf16 [4][32][1024]  262144
#define OB_MISC  27590656u                       // fp32 misc
// misc float offsets
#define MS_START 0
#define MS_END   1280
#define MS_TOS   2560
#define MS_TOE   2592

typedef short bf8 __attribute__((ext_vector_type(8)));   // 8 bf16 = 4 VGPRs
typedef short bf4 __attribute__((ext_vector_type(4)));   // 4 bf16 = 2 VGPRs
typedef float f4  __attribute__((ext_vector_type(4)));   // accumulator

static __device__ __forceinline__ unsigned short f2b(float f) {
    unsigned int x = __float_as_uint(f);
    unsigned int r = x + 0x7FFFu + ((x >> 16) & 1u);     // RNE
    return (unsigned short)(r >> 16);
}
static __device__ __forceinline__ unsigned int pk2(float lo, float hi) {
    return (unsigned int)f2b(lo) | ((unsigned int)f2b(hi) << 16);
}
static __device__ __forceinline__ float b2f16(unsigned short u) {
    return __uint_as_float((unsigned int)u << 16);
}
static __device__ __forceinline__ float blo(unsigned int u) {
    return __uint_as_float(u << 16);
}
static __device__ __forceinline__ float bhi(unsigned int u) {
    return __uint_as_float(u & 0xffff0000u);
}

// block (256 thr) reduction of two values via wave shuffle + 4 partials.
static __device__ __forceinline__ void block_reduce2(float& a, float& b, float* scr) {
    #pragma unroll
    for (int off = 32; off > 0; off >>= 1) {
        a += __shfl_down(a, off);
        b += __shfl_down(b, off);
    }
    int wv = threadIdx.x >> 6, lane = threadIdx.x & 63;
    __syncthreads();                         // protect scr reuse across calls
    if (lane == 0) { scr[wv] = a; scr[4 + wv] = b; }
    __syncthreads();
    a = scr[0] + scr[1] + scr[2] + scr[3];
    b = scr[4] + scr[5] + scr[6] + scr[7];
}

// ==== launch 1: w0 transpose (z<3) + prologue (z==3) ====
__global__ __launch_bounds__(256) void k_setup(const float* __restrict__ w0,
                                               unsigned short* __restrict__ w0t,
                                               const float* __restrict__ txt,
                                               const float* __restrict__ pw,
                                               const float* __restrict__ pb,
                                               const float* __restrict__ spans,
                                               unsigned short* __restrict__ txtb,
                                               float* __restrict__ msc) {
    int z = blockIdx.z, tid = threadIdx.x;
    if (z == 3) {
        int flat = blockIdx.x * 16 + blockIdx.y;
        if (flat < B_) {
            int b = flat;
            int h4 = tid * 4;
            float4 tv = *(const float4*)(txt + (size_t)b * H_ + h4);
            float4 pa = *(const float4*)(pw + 2 * h4);
            float4 pc = *(const float4*)(pw + 2 * h4 + 4);
            float s0 = tv.x * pa.x + tv.y * pa.z + tv.z * pc.x + tv.w * pc.z;
            float s1 = tv.x * pa.y + tv.y * pa.w + tv.z * pc.y + tv.w * pc.w;
            ushort4 o;
            o.x = f2b(tv.x); o.y = f2b(tv.y); o.z = f2b(tv.z); o.w = f2b(tv.w);
            *(ushort4*)(txtb + (size_t)b * H_ + h4) = o;
            __shared__ float scr[8];
            block_reduce2(s0, s1, scr);
            if (tid == 0) {
                const float half_lr = 4.9999975e-07f;   // 0.5*log(1.000001)
                msc[MS_TOS + b] = tanhf(s0 + pb[0]) * half_lr;
                msc[MS_TOE + b] = tanhf(s1 + pb[1]) * half_lr;
            }
        } else if (flat < 37) {
            int i = (flat - B_) * 256 + tid;
            if (i < M_) {
                float c = spans[2 * i], w = spans[2 * i + 1];
                msc[MS_START + i] = fminf(fmaxf(c - 0.5f * w, 0.f), 1.f);
                msc[MS_END + i]   = fminf(fmaxf(c + 0.5f * w, 0.f), 1.f);
            }
        }
        return;
    }
    // w0 [3072][1024] -> w0t [1024][3072], chunk z covers rows z*1024..+1023
    __shared__ float tile[64][69];
    const float* s = w0 + (size_t)z * 1024 * H_;
    unsigned short* d = w0t + (size_t)z * 1024;
    int r0 = blockIdx.x * 64, c0 = blockIdx.y * 64;
    int col4 = (tid & 15) * 4, row = tid >> 4;
    #pragma unroll
    for (int it = 0; it < 4; it++) {
        int r = it * 16 + row;
        float4 v = *(const float4*)(s + (size_t)(r0 + r) * 1024 + c0 + col4);
        *(float4*)(&tile[r][col4]) = v;
    }
    __syncthreads();
    #pragma unroll
    for (int it = 0; it < 2; it++) {
        int slot = it * 256 + tid;
        int c = slot >> 3, chunk = slot & 7;
        int r = chunk * 8;
        uint4 vv;
        vv.x = (unsigned int)f2b(tile[r + 0][c]) | ((unsigned int)f2b(tile[r + 1][c]) << 16);
        vv.y = (unsigned int)f2b(tile[r + 2][c]) | ((unsigned int)f2b(tile[r + 3][c]) << 16);
        vv.z = (unsigned int)f2b(tile[r + 4][c]) | ((unsigned int)f2b(tile[r + 5][c]) << 16);
        vv.w = (unsigned int)f2b(tile[r + 6][c]) | ((unsigned int)f2b(tile[r + 7][c]) << 16);
        *(uint4*)(d + (size_t)(c0 + c) * K3_ + r0 + r) = vv;
    }
}

// ---- shared device body: Gaussian weights for row m given spans ----
static __device__ __forceinline__ void weights_body(int m, float s, float e,
                                                    const float* __restrict__ vmask,
                                                    float ls_s, float ls_e,
                                                    float sw_s, float sw_e,
                                                    const float* __restrict__ msc,
                                                    unsigned short* __restrict__ wt2,
                                                    float* scr) {
    int b = m / Q_, q = m - b * Q_;
    int tid = threadIdx.x;
    float width = fmaxf(e - s, 1e-6f);
    const float min_sig = 1.0f / (4.0f * (float)L_);
    float sig_s = fmaxf(expf(ls_s + sw_s * width + msc[MS_TOS + b]), min_sig);
    float sig_e = fmaxf(expf(ls_e + sw_e * width + msc[MS_TOE + b]), min_sig);
    float inv_s = 1.0f / sig_s, inv_e = 1.0f / sig_e;

    float wsv[4], wev[4], sumS = 0.f, sumE = 0.f;
    #pragma unroll
    for (int k = 0; k < 4; k++) {
        int l = tid + k * 256;
        float t = (float)l * (1.0f / 1023.0f);
        float mk = vmask[b * L_ + l];
        float ds = (t - s) * inv_s, de = (t - e) * inv_e;
        float a = expf(-0.5f * ds * ds) * mk;
        float c = expf(-0.5f * de * de) * mk;
        wsv[k] = a; wev[k] = c; sumS += a; sumE += c;
    }
    block_reduce2(sumS, sumE, scr);
    float iS = 1.0f / fmaxf(sumS, 1e-8f);
    float iE = 1.0f / fmaxf(sumE, 1e-8f);
    unsigned short* wq = wt2 + ((size_t)b * QQ_ + q) * L_;
    unsigned short* we = wt2 + ((size_t)b * QQ_ + Q_ + q) * L_;
    #pragma unroll
    for (int k = 0; k < 4; k++) {
        int l = tid + k * 256;
        wq[l] = f2b(wsv[k] * iS);
        we[l] = f2b(wev[k] * iE);
    }
}

// ==== launch 2: weights(pass0) [bid<1280] + txt_mlp0 [bid>=1280] ====
__global__ __launch_bounds__(256) void k_stage2(const float* __restrict__ vmask,
                                                const float* __restrict__ p_ls_s,
                                                const float* __restrict__ p_ls_e,
                                                const float* __restrict__ p_sw_s,
                                                const float* __restrict__ p_sw_e,
                                                const float* __restrict__ msc,
                                                unsigned short* __restrict__ wt2,
                                                const unsigned short* __restrict__ txtb,
                                                const unsigned short* __restrict__ w0t,
                                                unsigned short* __restrict__ txtp) {
    int bid = blockIdx.x;
    if (bid < M_) {
        __shared__ float scr[8];
        int m = bid;
        weights_body(m, msc[MS_START + m], msc[MS_END + m], vmask,
                     p_ls_s[0], p_ls_e[0], p_sw_s[0], p_sw_e[0], msc, wt2, scr);
        return;
    }
    int t = bid - M_;                    // 0..127
    int nIdx = t & 15, mIdx = (t >> 4) & 1, kIdx = t >> 5;
    int wv = threadIdx.x >> 6, lane = threadIdx.x & 63;
    int ml = lane & 15, kg = lane >> 4;
    int mbase = mIdx * 16;
    int nbase = nIdx * 64 + wv * 16;
    int kz = kIdx * 256;
    const unsigned short* ap = txtb + ((size_t)(mbase + ml) * H_ + kz + kg * 8);
    const unsigned short* bp = w0t + ((size_t)(nbase + ml) * K3_ + JK_ + kz + kg * 8);
    f4 acc = (f4){0.f, 0.f, 0.f, 0.f};
    #pragma unroll
    for (int k0 = 0; k0 < 256; k0 += 32) {
        bf8 a = *(const bf8*)(ap + k0);
        bf8 bb = *(const bf8*)(bp + k0);
        acc = __builtin_amdgcn_mfma_f32_16x16x32_bf16(a, bb, acc, 0, 0, 0);
    }
    unsigned short* pp = txtp + (size_t)kIdx * B_ * H_;
    int n = nbase + ml;
    #pragma unroll
    for (int r = 0; r < 4; r++) {
        int m = mbase + kg * 4 + r;
        pp[(size_t)m * H_ + n] = f2b(acc[r]);
    }
}

// ==== pool via MFMA: 4 waves, full-K per wave, 64-l chunks, T14 stage split ====
// grid (B, 16); block 256 = 4 waves; wave = hsub (16-h slice of the 64-h tile)
// B tile per buf: [64 l][64 h] bf16 as 64 subtiles [4l][16h]:
//   sid = ((l5*4 + h16)*2 + s)*4 + kg   (l = l5*32 + kg*8 + s*4 + lr)
//   wave hsub, k-group s2(=l5): region byte off = (s2*4+hsub)*1024, tr pair +0/+512
// A tile per buf: [80 qq][72] ushorts (64 k + 8 pad; 144B rows, cluster-uniform)
__global__ __launch_bounds__(256) void k_pool_mfma(const float* __restrict__ vid,
                                                   const unsigned short* __restrict__ wt2,
                                                   unsigned short* __restrict__ joint) {
    int b = blockIdx.x, ht = blockIdx.y;
    int tid = threadIdx.x;
    int hsub = tid >> 6, lane = tid & 63;
    int ml = lane & 15, kg = lane >> 4;
    int h0 = ht * 64;

    __shared__ __align__(16) unsigned short tb[2][4096];       // 16 KB  B tiles
    __shared__ __align__(16) unsigned short ta[2][80 * 72];    // 23 KB  A tiles

    // --- B staging mapping: thread covers (l0, l0+32) x 8 h ---
    int l0 = tid >> 3;                // 0..31
    int h8 = (tid & 7) * 8;           // 0..56
    int sB = (l0 >> 2) & 1, kgB = l0 >> 3, lrB = l0 & 3;
    int h16 = h8 >> 4, hc = h8 & 15;
    int b_off = ((((h16) * 2 + sB) * 4 + kgB) * 64) + lrB * 16 + hc;   // l5=0; +2048 for l5=1
    const float* vbase = vid + (size_t)b * L_ * H_ + h0 + h8;

    const unsigned short* awsrc = wt2 + (size_t)b * QQ_ * L_;

    f4 acc[5];
    #pragma unroll
    for (int t = 0; t < 5; t++) acc[t] = (f4){0.f, 0.f, 0.f, 0.f};

    // prefetch registers
    float4 pv0, pv1, pv2, pv3;        // B: (l0: h8..h8+7), (l0+32: h8..h8+7)
    uint4 av0, av1, av2;              // A chunks (av2 only if tid<128)

    auto issueB = [&](int c) {
        const float* src = vbase + (size_t)(c * 64 + l0) * H_;
        pv0 = *(const float4*)(src);
        pv1 = *(const float4*)(src + 4);
        pv2 = *(const float4*)(src + 32 * H_);
        pv3 = *(const float4*)(src + 32 * H_ + 4);
    };
    auto issueA = [&](int c) {
        // 640 uint4 chunks: idx -> row=idx>>3, seg=idx&7 (8 ushorts at k=c*64+seg*8)
        int i0 = tid, i1 = tid + 256;
        av0 = *(const uint4*)(awsrc + (size_t)(i0 >> 3) * L_ + c * 64 + (i0 & 7) * 8);
        av1 = *(const uint4*)(awsrc + (size_t)(i1 >> 3) * L_ + c * 64 + (i1 & 7) * 8);
        if (tid < 128) {
            int i2 = tid + 512;
            av2 = *(const uint4*)(awsrc + (size_t)(i2 >> 3) * L_ + c * 64 + (i2 & 7) * 8);
        }
    };
    auto writeStage = [&](int buf) {
        uint4 w;
        w.x = pk2(pv0.x, pv0.y); w.y = pk2(pv0.z, pv0.w);
        w.z = pk2(pv1.x, pv1.y); w.w = pk2(pv1.z, pv1.w);
        *(uint4*)(&tb[buf][b_off]) = w;
        uint4 w2;
        w2.x = pk2(pv2.x, pv2.y); w2.y = pk2(pv2.z, pv2.w);
        w2.z = pk2(pv3.x, pv3.y); w2.w = pk2(pv3.z, pv3.w);
        *(uint4*)(&tb[buf][b_off + 2048]) = w2;
        int i0 = tid, i1 = tid + 256;
        *(uint4*)(&ta[buf][(i0 >> 3) * 72 + (i0 & 7) * 8]) = av0;
        *(uint4*)(&ta[buf][(i1 >> 3) * 72 + (i1 & 7) * 8]) = av1;
        if (tid < 128) {
            int i2 = tid + 512;
            *(uint4*)(&ta[buf][(i2 >> 3) * 72 + (i2 & 7) * 8]) = av2;
        }
    };

    // prologue: stage chunk 0 into buf 0
    issueB(0); issueA(0);
    writeStage(0);
    __syncthreads();

    for (int c = 0; c < 16; c++) {
        int buf = c & 1;
        if (c < 15) { issueB(c + 1); issueA(c + 1); }   // HBM/L2 loads in flight

        // compute on buf: 2 k-groups of 32, 5 qq-tiles each
        #pragma unroll
        for (int s2 = 0; s2 < 2; s2++) {
            unsigned trb = (unsigned)(uintptr_t)(&tb[buf][0]) + (s2 * 4 + hsub) * 1024
                           + lane * 8;
            bf4 lo, hi;
            asm volatile("ds_read_b64_tr_b16 %0, %2\n\t"
                         "ds_read_b64_tr_b16 %1, %2 offset:512\n\t"
                         "s_waitcnt lgkmcnt(0)"
                         : "=v"(lo), "=v"(hi)
                         : "v"(trb));
            __builtin_amdgcn_sched_barrier(0);
            bf8 bfrag = __builtin_shufflevector(lo, hi, 0, 1, 2, 3, 4, 5, 6, 7);
            #pragma unroll
            for (int t = 0; t < 5; t++) {
                bf8 afr = *(const bf8*)(&ta[buf][(t * 16 + ml) * 72 + s2 * 32 + kg * 8]);
                acc[t] = __builtin_amdgcn_mfma_f32_16x16x32_bf16(afr, bfrag, acc[t], 0, 0, 0);
            }
        }

        if (c < 15) writeStage(buf ^ 1);    // vmcnt wait lands here, after MFMA
        __syncthreads();
    }

    // epilogue: wave owns full K -> direct store. C: col=ml (h), row=kg*4+r (qq)
    #pragma unroll
    for (int t = 0; t < 5; t++) {
        #pragma unroll
        for (int r = 0; r < 4; r++) {
            int qq = t * 16 + kg * 4 + r;
            int row = b * Q_ + (qq >= Q_ ? qq - Q_ : qq);
            int col = (qq >= Q_ ? H_ : 0) + h0 + hsub * 16 + ml;
            joint[(size_t)row * JK_ + col] = f2b(acc[t][r]);
        }
    }
}

// ==== MLP0 via MFMA over feat-K (2048), K-split x4, + txtpart in epilogue ====
__global__ __launch_bounds__(256) void k_mlp0_mfma(const unsigned short* __restrict__ joint,
                                                   const unsigned short* __restrict__ w0t,
                                                   const unsigned short* __restrict__ txtp,
                                                   unsigned short* __restrict__ part) {
    int wv = threadIdx.x >> 6, lane = threadIdx.x & 63;
    int ml = lane & 15, kg = lane >> 4;
    int mbase = blockIdx.x * 64 + wv * 16;
    int nbase = blockIdx.y * 64;
    int kbase = blockIdx.z * 512;
    const unsigned short* ap = joint + ((size_t)(mbase + ml) * JK_ + kbase + kg * 8);
    const unsigned short* bp = w0t + ((size_t)(nbase + ml) * K3_ + kbase + kg * 8);
    f4 acc[4];
    #pragma unroll
    for (int t = 0; t < 4; t++) acc[t] = (f4){0.f, 0.f, 0.f, 0.f};

    #pragma unroll 4
    for (int k0 = 0; k0 < 512; k0 += 32) {
        bf8 a = *(const bf8*)(ap + k0);
        #pragma unroll
        for (int t = 0; t < 4; t++) {
            bf8 bb = *(const bf8*)(bp + (size_t)t * 16 * K3_ + k0);
            acc[t] = __builtin_amdgcn_mfma_f32_16x16x32_bf16(a, bb, acc[t], 0, 0, 0);
        }
    }
    const unsigned short* tp = txtp + (size_t)blockIdx.z * B_ * H_;
    unsigned short* pp = part + (size_t)blockIdx.z * M_ * H_;
    #pragma unroll
    for (int t = 0; t < 4; t++) {
        int n = nbase + t * 16 + ml;
        #pragma unroll
        for (int r = 0; r < 4; r++) {
            int m = mbase + kg * 4 + r;
            int b = m / Q_;
            float v = acc[t][r] + b2f16(tp[(size_t)b * H_ + n]);
            pp[(size_t)m * H_ + n] = f2b(v);
        }
    }
}

// ==== MLP1 + span update + outputs (+ weights for NEXT pass if do_weights) ====
__global__ __launch_bounds__(256) void k_mlp1w(const float* __restrict__ w1,
                                               const float* __restrict__ b0,
                                               const float* __restrict__ b1,
                                               const unsigned short* __restrict__ part,
                                               float* __restrict__ msc,
                                               float* __restrict__ out, int pass,
                                               int do_weights,
                                               const float* __restrict__ vmask,
                                               const float* __restrict__ p_ls_s,
                                               const float* __restrict__ p_ls_e,
                                               const float* __restrict__ p_sw_s,
                                               const float* __restrict__ p_sw_e,
                                               unsigned short* __restrict__ wt2) {
    int m = blockIdx.x, tid = threadIdx.x;
    int k4 = tid * 4;
    float4 bb = *(const float4*)(b0 + k4);
    float h0 = bb.x, h1 = bb.y, h2 = bb.z, h3 = bb.w;
    #pragma unroll
    for (int z = 0; z < 4; z++) {
        uint2 u = *(const uint2*)(part + (size_t)z * M_ * H_ + (size_t)m * H_ + k4);
        h0 += blo(u.x); h1 += bhi(u.x);
        h2 += blo(u.y); h3 += bhi(u.y);
    }
    h0 = fmaxf(h0, 0.f); h1 = fmaxf(h1, 0.f);
    h2 = fmaxf(h2, 0.f); h3 = fmaxf(h3, 0.f);
    float4 wa = *(const float4*)(w1 + 2 * k4);
    float4 wb = *(const float4*)(w1 + 2 * k4 + 4);
    float p0 = h0 * wa.x + h1 * wa.z + h2 * wb.x + h3 * wb.z;
    float p1 = h0 * wa.y + h1 * wa.w + h2 * wb.y + h3 * wb.w;

    __shared__ float scr[8];
    __shared__ float sh_s, sh_e;
    block_reduce2(p0, p1, scr);
    if (tid == 0) {
        float d0 = tanhf(p0 + b1[0]) * 0.1f;
        float d1 = tanhf(p1 + b1[1]) * 0.1f;
        float s = fminf(fmaxf(msc[MS_START + m] + d0, 0.f), 1.f);
        float e = fminf(fmaxf(msc[MS_END + m] + d1, 0.f), 1.f);
        msc[MS_START + m] = s;
        msc[MS_END + m] = e;
        sh_s = s; sh_e = e;
        float cen = 0.5f * (s + e);
        float wid = fmaxf(e - s, 1e-6f);
        out[2560 + (size_t)(pass * M_ + m) * 2 + 0] = cen;
        out[2560 + (size_t)(pass * M_ + m) * 2 + 1] = wid;
        if (pass == 1) { out[2 * m + 0] = cen; out[2 * m + 1] = wid; }
    }
    __syncthreads();
    if (do_weights) {
        weights_body(m, sh_s, sh_e, vmask,
                     p_ls_s[0], p_ls_e[0], p_sw_s[0], p_sw_e[0], msc, wt2, scr);
    }
}

extern "C" void kernel_launch(void* const* d_in, const int* in_sizes, int n_in,
                              void* d_out, int out_size, void* d_ws, size_t ws_size,
                              hipStream_t stream) {
    const float* spans = (const float*)d_in[0];
    const float* vid   = (const float*)d_in[1];
    const float* vmask = (const float*)d_in[2];
    const float* txt   = (const float*)d_in[3];
    const float* ls_s  = (const float*)d_in[4];
    const float* ls_e  = (const float*)d_in[5];
    const float* sw_s  = (const float*)d_in[6];
    const float* sw_e  = (const float*)d_in[7];
    const float* pw    = (const float*)d_in[8];
    const float* pb    = (const float*)d_in[9];
    const float* w0    = (const float*)d_in[10];
    const float* b0    = (const float*)d_in[11];
    const float* w1    = (const float*)d_in[12];
    const float* b1    = (const float*)d_in[13];
    char* wsb = (char*)d_ws;
    unsigned short* w0t   = (unsigned short*)(wsb + OB_W0T);
    unsigned short* wt2   = (unsigned short*)(wsb + OB_WT2);
    unsigned short* joint = (unsigned short*)(wsb + OB_JOINT);
    unsigned short* part  = (unsigned short*)(wsb + OB_PART);
    unsigned short* txtb  = (unsigned short*)(wsb + OB_TXTB);
    unsigned short* txtp  = (unsigned short*)(wsb + OB_TXTP);
    float* msc = (float*)(wsb + OB_MISC);
    float* out = (float*)d_out;

    hipLaunchKernelGGL(k_setup, dim3(16, 16, 4), dim3(256), 0, stream,
                       w0, w0t, txt, pw, pb, spans, txtb, msc);
    hipLaunchKernelGGL(k_stage2, dim3(M_ + 128), dim3(256), 0, stream,
                       vmask, ls_s, ls_e, sw_s, sw_e, msc, wt2, txtb, w0t, txtp);
    for (int p = 0; p < 2; p++) {
        hipLaunchKernelGGL(k_pool_mfma, dim3(B_, 16), dim3(256), 0, stream, vid, wt2, joint);
        hipLaunchKernelGGL(k_mlp0_mfma, dim3(20, 16, 4), dim3(256), 0, stream,
                           joint, w0t, txtp, part);
        hipLaunchKernelGGL(k_mlp1w, dim3(M_), dim3(256), 0, stream,
                           w1, b0, b1, part, msc, out, p, (p == 0) ? 1 : 0,
                           vmask, ls_s, ls_e, sw_s, sw_e, wt2);
    }
}

// Round 4
// 361.059 us; speedup vs baseline: 1.0112x; 1.0112x over previous
//
#include <hip/hip_runtime.h>

// Problem constants
#define B_   32
#define Q_   40
#define L_   1024
#define H_   1024
#define QQ_  80
#define M_   1280          // B_*Q_
#define K3_  3072
#define JK_  2048          // joint holds only the two pooled-feature thirds

// Workspace layout (BYTE offsets)
#define OB_W0T   0u                              // bf16 [1024][3072]  6291456
#define OB_WT2   6291456u                        // bf16 [B][80][L]    5242880
#define OB_JOINT 11534336u                       // bf16 [M][2048]     5242880
#define OB_PART  16777216u                       // bf16 [4][M][1024] 10485760
#define OB_TXTB  27262976u                       // bf16 [32][1024]      65536
#define OB_TXTP  27328512u                       // bf16 [4][32][1024]  262144
#define OB_MISC  27590656u                       // fp32 misc
// misc float offsets
#define MS_START 0
#define MS_END   1280
#define MS_TOS   2560
#define MS_TOE   2592

typedef short bf8 __attribute__((ext_vector_type(8)));   // 8 bf16 = 4 VGPRs
typedef short bf4 __attribute__((ext_vector_type(4)));   // 4 bf16 = 2 VGPRs
typedef float f4  __attribute__((ext_vector_type(4)));   // accumulator

static __device__ __forceinline__ unsigned short f2b(float f) {
    unsigned int x = __float_as_uint(f);
    unsigned int r = x + 0x7FFFu + ((x >> 16) & 1u);     // RNE
    return (unsigned short)(r >> 16);
}
static __device__ __forceinline__ unsigned int pk2(float lo, float hi) {
    return (unsigned int)f2b(lo) | ((unsigned int)f2b(hi) << 16);
}
static __device__ __forceinline__ float b2f16(unsigned short u) {
    return __uint_as_float((unsigned int)u << 16);
}
static __device__ __forceinline__ float blo(unsigned int u) {
    return __uint_as_float(u << 16);
}
static __device__ __forceinline__ float bhi(unsigned int u) {
    return __uint_as_float(u & 0xffff0000u);
}

// block (256 thr) reduction of two values via wave shuffle + 4 partials.
static __device__ __forceinline__ void block_reduce2(float& a, float& b, float* scr) {
    #pragma unroll
    for (int off = 32; off > 0; off >>= 1) {
        a += __shfl_down(a, off);
        b += __shfl_down(b, off);
    }
    int wv = threadIdx.x >> 6, lane = threadIdx.x & 63;
    __syncthreads();                         // protect scr reuse across calls
    if (lane == 0) { scr[wv] = a; scr[4 + wv] = b; }
    __syncthreads();
    a = scr[0] + scr[1] + scr[2] + scr[3];
    b = scr[4] + scr[5] + scr[6] + scr[7];
}

// ---- Gaussian weights core for row m, txt offsets passed in ----
static __device__ __forceinline__ void weights_core(int m, float s, float e,
                                                    float toff_s, float toff_e,
                                                    const float* __restrict__ vmask,
                                                    float ls_s, float ls_e,
                                                    float sw_s, float sw_e,
                                                    unsigned short* __restrict__ wt2,
                                                    float* scr) {
    int b = m / Q_, q = m - b * Q_;
    int tid = threadIdx.x;
    float width = fmaxf(e - s, 1e-6f);
    const float min_sig = 1.0f / (4.0f * (float)L_);
    float sig_s = fmaxf(expf(ls_s + sw_s * width + toff_s), min_sig);
    float sig_e = fmaxf(expf(ls_e + sw_e * width + toff_e), min_sig);
    float inv_s = 1.0f / sig_s, inv_e = 1.0f / sig_e;

    float wsv[4], wev[4], sumS = 0.f, sumE = 0.f;
    #pragma unroll
    for (int k = 0; k < 4; k++) {
        int l = tid + k * 256;
        float t = (float)l * (1.0f / 1023.0f);
        float mk = vmask[b * L_ + l];
        float ds = (t - s) * inv_s, de = (t - e) * inv_e;
        float a = expf(-0.5f * ds * ds) * mk;
        float c = expf(-0.5f * de * de) * mk;
        wsv[k] = a; wev[k] = c; sumS += a; sumE += c;
    }
    block_reduce2(sumS, sumE, scr);
    float iS = 1.0f / fmaxf(sumS, 1e-8f);
    float iE = 1.0f / fmaxf(sumE, 1e-8f);
    unsigned short* wq = wt2 + ((size_t)b * QQ_ + q) * L_;
    unsigned short* we = wt2 + ((size_t)b * QQ_ + Q_ + q) * L_;
    #pragma unroll
    for (int k = 0; k < 4; k++) {
        int l = tid + k * 256;
        wq[l] = f2b(wsv[k] * iS);
        we[l] = f2b(wev[k] * iE);
    }
}

// ---- weights with txt offsets from msc (used by mlp1w for pass-1) ----
static __device__ __forceinline__ void weights_body(int m, float s, float e,
                                                    const float* __restrict__ vmask,
                                                    float ls_s, float ls_e,
                                                    float sw_s, float sw_e,
                                                    const float* __restrict__ msc,
                                                    unsigned short* __restrict__ wt2,
                                                    float* scr) {
    int b = m / Q_;
    weights_core(m, s, e, msc[MS_TOS + b], msc[MS_TOE + b],
                 vmask, ls_s, ls_e, sw_s, sw_e, wt2, scr);
}

// ==== launch 1: w0 transpose (z<3) + prologue (z==3) + pass-0 weights (z>=4) ====
__global__ __launch_bounds__(256) void k_setup(const float* __restrict__ w0,
                                               unsigned short* __restrict__ w0t,
                                               const float* __restrict__ txt,
                                               const float* __restrict__ pw,
                                               const float* __restrict__ pb,
                                               const float* __restrict__ spans,
                                               unsigned short* __restrict__ txtb,
                                               float* __restrict__ msc,
                                               const float* __restrict__ vmask,
                                               const float* __restrict__ p_ls_s,
                                               const float* __restrict__ p_ls_e,
                                               const float* __restrict__ p_sw_s,
                                               const float* __restrict__ p_sw_e,
                                               unsigned short* __restrict__ wt2) {
    int z = blockIdx.z, tid = threadIdx.x;
    if (z >= 4) {
        // pass-0 weights, fully self-contained (no cross-block deps):
        // recompute this batch's txt_off with arithmetic identical to z==3.
        int m = (z - 4) * 256 + (blockIdx.x * 16 + blockIdx.y);
        int b = m / Q_;
        int h4 = tid * 4;
        float4 tv = *(const float4*)(txt + (size_t)b * H_ + h4);
        float4 pa = *(const float4*)(pw + 2 * h4);
        float4 pc = *(const float4*)(pw + 2 * h4 + 4);
        float s0 = tv.x * pa.x + tv.y * pa.z + tv.z * pc.x + tv.w * pc.z;
        float s1 = tv.x * pa.y + tv.y * pa.w + tv.z * pc.y + tv.w * pc.w;
        __shared__ float scrW[8];
        block_reduce2(s0, s1, scrW);
        const float half_lr = 4.9999975e-07f;   // 0.5*log(1.000001)
        float toff_s = tanhf(s0 + pb[0]) * half_lr;
        float toff_e = tanhf(s1 + pb[1]) * half_lr;
        float c = spans[2 * m], w = spans[2 * m + 1];
        float s = fminf(fmaxf(c - 0.5f * w, 0.f), 1.f);
        float e = fminf(fmaxf(c + 0.5f * w, 0.f), 1.f);
        weights_core(m, s, e, toff_s, toff_e, vmask,
                     p_ls_s[0], p_ls_e[0], p_sw_s[0], p_sw_e[0], wt2, scrW);
        return;
    }
    if (z == 3) {
        int flat = blockIdx.x * 16 + blockIdx.y;
        if (flat < B_) {
            int b = flat;
            int h4 = tid * 4;
            float4 tv = *(const float4*)(txt + (size_t)b * H_ + h4);
            float4 pa = *(const float4*)(pw + 2 * h4);
            float4 pc = *(const float4*)(pw + 2 * h4 + 4);
            float s0 = tv.x * pa.x + tv.y * pa.z + tv.z * pc.x + tv.w * pc.z;
            float s1 = tv.x * pa.y + tv.y * pa.w + tv.z * pc.y + tv.w * pc.w;
            ushort4 o;
            o.x = f2b(tv.x); o.y = f2b(tv.y); o.z = f2b(tv.z); o.w = f2b(tv.w);
            *(ushort4*)(txtb + (size_t)b * H_ + h4) = o;
            __shared__ float scr[8];
            block_reduce2(s0, s1, scr);
            if (tid == 0) {
                const float half_lr = 4.9999975e-07f;   // 0.5*log(1.000001)
                msc[MS_TOS + b] = tanhf(s0 + pb[0]) * half_lr;
                msc[MS_TOE + b] = tanhf(s1 + pb[1]) * half_lr;
            }
        } else if (flat < 37) {
            int i = (flat - B_) * 256 + tid;
            if (i < M_) {
                float c = spans[2 * i], w = spans[2 * i + 1];
                msc[MS_START + i] = fminf(fmaxf(c - 0.5f * w, 0.f), 1.f);
                msc[MS_END + i]   = fminf(fmaxf(c + 0.5f * w, 0.f), 1.f);
            }
        }
        return;
    }
    // w0 [3072][1024] -> w0t [1024][3072], chunk z covers rows z*1024..+1023
    __shared__ float tile[64][69];
    const float* s = w0 + (size_t)z * 1024 * H_;
    unsigned short* d = w0t + (size_t)z * 1024;
    int r0 = blockIdx.x * 64, c0 = blockIdx.y * 64;
    int col4 = (tid & 15) * 4, row = tid >> 4;
    #pragma unroll
    for (int it = 0; it < 4; it++) {
        int r = it * 16 + row;
        float4 v = *(const float4*)(s + (size_t)(r0 + r) * 1024 + c0 + col4);
        *(float4*)(&tile[r][col4]) = v;
    }
    __syncthreads();
    #pragma unroll
    for (int it = 0; it < 2; it++) {
        int slot = it * 256 + tid;
        int c = slot >> 3, chunk = slot & 7;
        int r = chunk * 8;
        uint4 vv;
        vv.x = (unsigned int)f2b(tile[r + 0][c]) | ((unsigned int)f2b(tile[r + 1][c]) << 16);
        vv.y = (unsigned int)f2b(tile[r + 2][c]) | ((unsigned int)f2b(tile[r + 3][c]) << 16);
        vv.z = (unsigned int)f2b(tile[r + 4][c]) | ((unsigned int)f2b(tile[r + 5][c]) << 16);
        vv.w = (unsigned int)f2b(tile[r + 6][c]) | ((unsigned int)f2b(tile[r + 7][c]) << 16);
        *(uint4*)(d + (size_t)(c0 + c) * K3_ + r0 + r) = vv;
    }
}

// ==== pool via MFMA: 4 waves, full-K per wave, 64-l chunks, T14 stage split ====
// grid (B, 16[+4]); block 256 = 4 waves; wave = hsub (16-h slice of the 64-h tile)
// blockIdx.y>=16 (launch #0 only): txt_mlp0 blocks (txtp is pass-invariant).
// B tile per buf: [64 l][64 h] bf16 as 64 subtiles [4l][16h]:
//   sid = ((l5*4 + h16)*2 + s)*4 + kg   (l = l5*32 + kg*8 + s*4 + lr)
//   wave hsub, k-group s2(=l5): region byte off = (s2*4+hsub)*1024, tr pair +0/+512
// A tile per buf: [80 qq][72] ushorts (64 k + 8 pad; 144B rows, cluster-uniform)
__global__ __launch_bounds__(256) void k_pool_mfma(const float* __restrict__ vid,
                                                   const unsigned short* __restrict__ wt2,
                                                   unsigned short* __restrict__ joint,
                                                   const unsigned short* __restrict__ txtb,
                                                   const unsigned short* __restrict__ w0t,
                                                   unsigned short* __restrict__ txtp) {
    if (blockIdx.y >= 16) {
        // txt_mlp0: txtb [32][1024] @ w0t-third -> txtp, 128 blocks
        int t = (blockIdx.y - 16) * 32 + blockIdx.x;     // 0..127
        int nIdx = t & 15, mIdx = (t >> 4) & 1, kIdx = t >> 5;
        int wv = threadIdx.x >> 6, lane = threadIdx.x & 63;
        int ml = lane & 15, kg = lane >> 4;
        int mbase = mIdx * 16;
        int nbase = nIdx * 64 + wv * 16;
        int kz = kIdx * 256;
        const unsigned short* ap = txtb + ((size_t)(mbase + ml) * H_ + kz + kg * 8);
        const unsigned short* bp = w0t + ((size_t)(nbase + ml) * K3_ + JK_ + kz + kg * 8);
        f4 acc = (f4){0.f, 0.f, 0.f, 0.f};
        #pragma unroll
        for (int k0 = 0; k0 < 256; k0 += 32) {
            bf8 a = *(const bf8*)(ap + k0);
            bf8 bb = *(const bf8*)(bp + k0);
            acc = __builtin_amdgcn_mfma_f32_16x16x32_bf16(a, bb, acc, 0, 0, 0);
        }
        unsigned short* pp = txtp + (size_t)kIdx * B_ * H_;
        int n = nbase + ml;
        #pragma unroll
        for (int r = 0; r < 4; r++) {
            int m = mbase + kg * 4 + r;
            pp[(size_t)m * H_ + n] = f2b(acc[r]);
        }
        return;
    }

    int b = blockIdx.x, ht = blockIdx.y;
    int tid = threadIdx.x;
    int hsub = tid >> 6, lane = tid & 63;
    int ml = lane & 15, kg = lane >> 4;
    int h0 = ht * 64;

    __shared__ __align__(16) unsigned short tb[2][4096];       // 16 KB  B tiles
    __shared__ __align__(16) unsigned short ta[2][80 * 72];    // 23 KB  A tiles

    // --- B staging mapping: thread covers (l0, l0+32) x 8 h ---
    int l0 = tid >> 3;                // 0..31
    int h8 = (tid & 7) * 8;           // 0..56
    int sB = (l0 >> 2) & 1, kgB = l0 >> 3, lrB = l0 & 3;
    int h16 = h8 >> 4, hc = h8 & 15;
    int b_off = ((((h16) * 2 + sB) * 4 + kgB) * 64) + lrB * 16 + hc;   // l5=0; +2048 for l5=1
    const float* vbase = vid + (size_t)b * L_ * H_ + h0 + h8;

    const unsigned short* awsrc = wt2 + (size_t)b * QQ_ * L_;

    f4 acc[5];
    #pragma unroll
    for (int t = 0; t < 5; t++) acc[t] = (f4){0.f, 0.f, 0.f, 0.f};

    // prefetch registers
    float4 pv0, pv1, pv2, pv3;        // B: (l0: h8..h8+7), (l0+32: h8..h8+7)
    uint4 av0, av1, av2;              // A chunks (av2 only if tid<128)

    auto issueB = [&](int c) {
        const float* src = vbase + (size_t)(c * 64 + l0) * H_;
        pv0 = *(const float4*)(src);
        pv1 = *(const float4*)(src + 4);
        pv2 = *(const float4*)(src + 32 * H_);
        pv3 = *(const float4*)(src + 32 * H_ + 4);
    };
    auto issueA = [&](int c) {
        // 640 uint4 chunks: idx -> row=idx>>3, seg=idx&7 (8 ushorts at k=c*64+seg*8)
        int i0 = tid, i1 = tid + 256;
        av0 = *(const uint4*)(awsrc + (size_t)(i0 >> 3) * L_ + c * 64 + (i0 & 7) * 8);
        av1 = *(const uint4*)(awsrc + (size_t)(i1 >> 3) * L_ + c * 64 + (i1 & 7) * 8);
        if (tid < 128) {
            int i2 = tid + 512;
            av2 = *(const uint4*)(awsrc + (size_t)(i2 >> 3) * L_ + c * 64 + (i2 & 7) * 8);
        }
    };
    auto writeStage = [&](int buf) {
        uint4 w;
        w.x = pk2(pv0.x, pv0.y); w.y = pk2(pv0.z, pv0.w);
        w.z = pk2(pv1.x, pv1.y); w.w = pk2(pv1.z, pv1.w);
        *(uint4*)(&tb[buf][b_off]) = w;
        uint4 w2;
        w2.x = pk2(pv2.x, pv2.y); w2.y = pk2(pv2.z, pv2.w);
        w2.z = pk2(pv3.x, pv3.y); w2.w = pk2(pv3.z, pv3.w);
        *(uint4*)(&tb[buf][b_off + 2048]) = w2;
        int i0 = tid, i1 = tid + 256;
        *(uint4*)(&ta[buf][(i0 >> 3) * 72 + (i0 & 7) * 8]) = av0;
        *(uint4*)(&ta[buf][(i1 >> 3) * 72 + (i1 & 7) * 8]) = av1;
        if (tid < 128) {
            int i2 = tid + 512;
            *(uint4*)(&ta[buf][(i2 >> 3) * 72 + (i2 & 7) * 8]) = av2;
        }
    };

    // prologue: stage chunk 0 into buf 0
    issueB(0); issueA(0);
    writeStage(0);
    __syncthreads();

    for (int c = 0; c < 16; c++) {
        int buf = c & 1;
        if (c < 15) { issueB(c + 1); issueA(c + 1); }   // HBM/L2 loads in flight

        // compute on buf: 2 k-groups of 32, 5 qq-tiles each
        #pragma unroll
        for (int s2 = 0; s2 < 2; s2++) {
            unsigned trb = (unsigned)(uintptr_t)(&tb[buf][0]) + (s2 * 4 + hsub) * 1024
                           + lane * 8;
            bf4 lo, hi;
            asm volatile("ds_read_b64_tr_b16 %0, %2\n\t"
                         "ds_read_b64_tr_b16 %1, %2 offset:512\n\t"
                         "s_waitcnt lgkmcnt(0)"
                         : "=v"(lo), "=v"(hi)
                         : "v"(trb));
            __builtin_amdgcn_sched_barrier(0);
            bf8 bfrag = __builtin_shufflevector(lo, hi, 0, 1, 2, 3, 4, 5, 6, 7);
            #pragma unroll
            for (int t = 0; t < 5; t++) {
                bf8 afr = *(const bf8*)(&ta[buf][(t * 16 + ml) * 72 + s2 * 32 + kg * 8]);
                acc[t] = __builtin_amdgcn_mfma_f32_16x16x32_bf16(afr, bfrag, acc[t], 0, 0, 0);
            }
        }

        if (c < 15) writeStage(buf ^ 1);    // vmcnt wait lands here, after MFMA
        __syncthreads();
    }

    // epilogue: wave owns full K -> direct store. C: col=ml (h), row=kg*4+r (qq)
    #pragma unroll
    for (int t = 0; t < 5; t++) {
        #pragma unroll
        for (int r = 0; r < 4; r++) {
            int qq = t * 16 + kg * 4 + r;
            int row = b * Q_ + (qq >= Q_ ? qq - Q_ : qq);
            int col = (qq >= Q_ ? H_ : 0) + h0 + hsub * 16 + ml;
            joint[(size_t)row * JK_ + col] = f2b(acc[t][r]);
        }
    }
}

// ==== MLP0 via MFMA over feat-K (2048), K-split x4, + txtpart in epilogue ====
__global__ __launch_bounds__(256) void k_mlp0_mfma(const unsigned short* __restrict__ joint,
                                                   const unsigned short* __restrict__ w0t,
                                                   const unsigned short* __restrict__ txtp,
                                                   unsigned short* __restrict__ part) {
    int wv = threadIdx.x >> 6, lane = threadIdx.x & 63;
    int ml = lane & 15, kg = lane >> 4;
    int mbase = blockIdx.x * 64 + wv * 16;
    int nbase = blockIdx.y * 64;
    int kbase = blockIdx.z * 512;
    const unsigned short* ap = joint + ((size_t)(mbase + ml) * JK_ + kbase + kg * 8);
    const unsigned short* bp = w0t + ((size_t)(nbase + ml) * K3_ + kbase + kg * 8);
    f4 acc[4];
    #pragma unroll
    for (int t = 0; t < 4; t++) acc[t] = (f4){0.f, 0.f, 0.f, 0.f};

    #pragma unroll 4
    for (int k0 = 0; k0 < 512; k0 += 32) {
        bf8 a = *(const bf8*)(ap + k0);
        #pragma unroll
        for (int t = 0; t < 4; t++) {
            bf8 bb = *(const bf8*)(bp + (size_t)t * 16 * K3_ + k0);
            acc[t] = __builtin_amdgcn_mfma_f32_16x16x32_bf16(a, bb, acc[t], 0, 0, 0);
        }
    }
    const unsigned short* tp = txtp + (size_t)blockIdx.z * B_ * H_;
    unsigned short* pp = part + (size_t)blockIdx.z * M_ * H_;
    #pragma unroll
    for (int t = 0; t < 4; t++) {
        int n = nbase + t * 16 + ml;
        #pragma unroll
        for (int r = 0; r < 4; r++) {
            int m = mbase + kg * 4 + r;
            int b = m / Q_;
            float v = acc[t][r] + b2f16(tp[(size_t)b * H_ + n]);
            pp[(size_t)m * H_ + n] = f2b(v);
        }
    }
}

// ==== MLP1 + span update + outputs (+ weights for NEXT pass if do_weights) ====
__global__ __launch_bounds__(256) void k_mlp1w(const float* __restrict__ w1,
                                               const float* __restrict__ b0,
                                               const float* __restrict__ b1,
                                               const unsigned short* __restrict__ part,
                                               float* __restrict__ msc,
                                               float* __restrict__ out, int pass,
                                               int do_weights,
                                               const float* __restrict__ vmask,
                                               const float* __restrict__ p_ls_s,
                                               const float* __restrict__ p_ls_e,
                                               const float* __restrict__ p_sw_s,
                                               const float* __restrict__ p_sw_e,
                                               unsigned short* __restrict__ wt2) {
    int m = blockIdx.x, tid = threadIdx.x;
    int k4 = tid * 4;
    float4 bb = *(const float4*)(b0 + k4);
    float h0 = bb.x, h1 = bb.y, h2 = bb.z, h3 = bb.w;
    #pragma unroll
    for (int z = 0; z < 4; z++) {
        uint2 u = *(const uint2*)(part + (size_t)z * M_ * H_ + (size_t)m * H_ + k4);
        h0 += blo(u.x); h1 += bhi(u.x);
        h2 += blo(u.y); h3 += bhi(u.y);
    }
    h0 = fmaxf(h0, 0.f); h1 = fmaxf(h1, 0.f);
    h2 = fmaxf(h2, 0.f); h3 = fmaxf(h3, 0.f);
    float4 wa = *(const float4*)(w1 + 2 * k4);
    float4 wb = *(const float4*)(w1 + 2 * k4 + 4);
    float p0 = h0 * wa.x + h1 * wa.z + h2 * wb.x + h3 * wb.z;
    float p1 = h0 * wa.y + h1 * wa.w + h2 * wb.y + h3 * wb.w;

    __shared__ float scr[8];
    __shared__ float sh_s, sh_e;
    block_reduce2(p0, p1, scr);
    if (tid == 0) {
        float d0 = tanhf(p0 + b1[0]) * 0.1f;
        float d1 = tanhf(p1 + b1[1]) * 0.1f;
        float s = fminf(fmaxf(msc[MS_START + m] + d0, 0.f), 1.f);
        float e = fminf(fmaxf(msc[MS_END + m] + d1, 0.f), 1.f);
        msc[MS_START + m] = s;
        msc[MS_END + m] = e;
        sh_s = s; sh_e = e;
        float cen = 0.5f * (s + e);
        float wid = fmaxf(e - s, 1e-6f);
        out[2560 + (size_t)(pass * M_ + m) * 2 + 0] = cen;
        out[2560 + (size_t)(pass * M_ + m) * 2 + 1] = wid;
        if (pass == 1) { out[2 * m + 0] = cen; out[2 * m + 1] = wid; }
    }
    __syncthreads();
    if (do_weights) {
        weights_body(m, sh_s, sh_e, vmask,
                     p_ls_s[0], p_ls_e[0], p_sw_s[0], p_sw_e[0], msc, wt2, scr);
    }
}

extern "C" void kernel_launch(void* const* d_in, const int* in_sizes, int n_in,
                              void* d_out, int out_size, void* d_ws, size_t ws_size,
                              hipStream_t stream) {
    const float* spans = (const float*)d_in[0];
    const float* vid   = (const float*)d_in[1];
    const float* vmask = (const float*)d_in[2];
    const float* txt   = (const float*)d_in[3];
    const float* ls_s  = (const float*)d_in[4];
    const float* ls_e  = (const float*)d_in[5];
    const float* sw_s  = (const float*)d_in[6];
    const float* sw_e  = (const float*)d_in[7];
    const float* pw    = (const float*)d_in[8];
    const float* pb    = (const float*)d_in[9];
    const float* w0    = (const float*)d_in[10];
    const float* b0    = (const float*)d_in[11];
    const float* w1    = (const float*)d_in[12];
    const float* b1    = (const float*)d_in[13];
    char* wsb = (char*)d_ws;
    unsigned short* w0t   = (unsigned short*)(wsb + OB_W0T);
    unsigned short* wt2   = (unsigned short*)(wsb + OB_WT2);
    unsigned short* joint = (unsigned short*)(wsb + OB_JOINT);
    unsigned short* part  = (unsigned short*)(wsb + OB_PART);
    unsigned short* txtb  = (unsigned short*)(wsb + OB_TXTB);
    unsigned short* txtp  = (unsigned short*)(wsb + OB_TXTP);
    float* msc = (float*)(wsb + OB_MISC);
    float* out = (float*)d_out;

    // setup: w0T + prologue + pass-0 weights (z=4..8 -> 1280 weight blocks)
    hipLaunchKernelGGL(k_setup, dim3(16, 16, 9), dim3(256), 0, stream,
                       w0, w0t, txt, pw, pb, spans, txtb, msc,
                       vmask, ls_s, ls_e, sw_s, sw_e, wt2);
    for (int p = 0; p < 2; p++) {
        // pool launch #0 carries the 128 txt_mlp0 blocks (y = 16..19)
        hipLaunchKernelGGL(k_pool_mfma, dim3(B_, (p == 0) ? 20 : 16), dim3(256), 0, stream,
                           vid, wt2, joint, txtb, w0t, txtp);
        hipLaunchKernelGGL(k_mlp0_mfma, dim3(20, 16, 4), dim3(256), 0, stream,
                           joint, w0t, txtp, part);
        hipLaunchKernelGGL(k_mlp1w, dim3(M_), dim3(256), 0, stream,
                           w1, b0, b1, part, msc, out, p, (p == 0) ? 1 : 0,
                           vmask, ls_s, ls_e, sw_s, sw_e, wt2);
    }
}